// Round 11
// baseline (213.060 us; speedup 1.0000x reference)
//
#include <hip/hip_runtime.h>
#include <math.h>

#define NCONST 100
#define NF     16
#define BLK    512

typedef _Float16 f16;
typedef _Float16 f16x8 __attribute__((ext_vector_type(8)));
typedef _Float16 f16x4 __attribute__((ext_vector_type(4)));
typedef float    f32x16 __attribute__((ext_vector_type(16)));

// ===================== MAIN: R9 monolith + ILP-2 edge =====================
// One block per batch element, 512 threads (8 waves).
// Edge phase: each wave runs TWO receivers (base, base+50) as independent
// interleaved chains -> 2 latency chains in flight per wave (R8/R9/R10 showed
// time invariant to occupancy/config => per-wave serial-chain bound).
// All per-tile math identical to R9 (HW-verified): 32x32x16 MFMA pair with b2
// folded at k=30, shfl_xor(32) h2 redistribute, b3 folded at k2=15.
__global__ __launch_bounds__(BLK, 4) void convint_fused(
    const float* __restrict__ x,
    const float* __restrict__ bn_g, const float* __restrict__ bn_b,
    const float* __restrict__ bn_m, const float* __restrict__ bn_v,
    const float* __restrict__ frw1, const float* __restrict__ frb1,
    const float* __restrict__ frw2, const float* __restrict__ frb2,
    const float* __restrict__ frw3, const float* __restrict__ frb3,
    const float* __restrict__ fow1, const float* __restrict__ fob1,
    const float* __restrict__ fow2, const float* __restrict__ fob2,
    const float* __restrict__ fow3, const float* __restrict__ fob3,
    const float* __restrict__ fcw1, const float* __restrict__ fcb1,
    const float* __restrict__ fcw2, const float* __restrict__ fcb2,
    float* __restrict__ out)
{
    __shared__ float xbn[NCONST][NF];
    __shared__ float upool[7200];
    __shared__ float aggF[NCONST * 8];
    __shared__ float fcin[8];
    __shared__ float hfc[48];
    __shared__ float logits[8];

    char* const PrB = (char*)upool;           // 8000 B, swizzled 16B slots
    char* const PsB = PrB + 8000;             // 8000 B
    float (*const foh1)[48] = (float (*)[48])upool;
    float (*const foh2)[24] = (float (*)[24])(upool + 4800);

    const int b   = blockIdx.x;
    const int tid = threadIdx.x;
    const float* xb = x + (size_t)b * (NCONST * NF);

    for (int idx = tid; idx < NCONST * NF; idx += BLK) {
        int f = idx & 15;
        float sc = rsqrtf(bn_v[f] + 1e-3f) * bn_g[f];
        xbn[idx >> 4][f] = (xb[idx] - bn_m[f]) * sc + bn_b[f];
    }
    if (tid < 8) fcin[tid] = 0.f;
    __syncthreads();

    // ---- proj (R9-verified) ----
    for (int idx = tid; idx < 1600; idx += BLK) {
        int n   = idx >> 4;
        int rem = idx & 15;
        int sel = rem >> 3;
        int oq  = rem & 7;
        int o0  = oq * 4;
        float xs[16];
        {
            const float4* xv = (const float4*)(&xbn[n][0]);
            float4 x0 = xv[0], x1 = xv[1], x2 = xv[2], x3 = xv[3];
            xs[0]=x0.x; xs[1]=x0.y; xs[2]=x0.z; xs[3]=x0.w;
            xs[4]=x1.x; xs[5]=x1.y; xs[6]=x1.z; xs[7]=x1.w;
            xs[8]=x2.x; xs[9]=x2.y; xs[10]=x2.z; xs[11]=x2.w;
            xs[12]=x3.x; xs[13]=x3.y; xs[14]=x3.z; xs[15]=x3.w;
        }
        float acc0 = (!sel) ? frb1[o0 + 0] : 0.f;
        float acc1 = (!sel) ? frb1[o0 + 1] : 0.f;
        float acc2 = (!sel && oq < 7) ? frb1[o0 + 2] : 0.f;
        float acc3 = (!sel && oq < 7) ? frb1[o0 + 3] : 0.f;
        const float* wbase = frw1 + sel * 16 * 30;
        const int wcol2 = (oq < 7) ? o0 + 2 : 28;
        #pragma unroll
        for (int f = 0; f < 16; ++f) {
            const float* wr = wbase + f * 30;
            float2 wa = *(const float2*)(wr + o0);
            float2 wb = *(const float2*)(wr + wcol2);
            acc0 = fmaf(xs[f], wa.x, acc0);
            acc1 = fmaf(xs[f], wa.y, acc1);
            acc2 = fmaf(xs[f], wb.x, acc2);
            acc3 = fmaf(xs[f], wb.y, acc3);
        }
        f16x4 hv;
        hv[0] = (f16)acc0;
        hv[1] = (f16)acc1;
        hv[2] = (oq < 7) ? (f16)acc2 : (sel ? (f16)0.f : (f16)1.f);
        hv[3] = (oq < 7) ? (f16)acc3 : (f16)0.f;
        int slot = oq >> 1;
        int sw = (slot & 2) | ((slot ^ (n >> 3)) & 1);
        *(f16x4*)((sel ? PsB : PrB) + n * 80 + sw * 16 + (oq & 1) * 8) = hv;
    }
    __syncthreads();

    // ---- edge, ILP-2 ----
    {
        const int l  = tid & 63;
        const int wv = tid >> 6;
        const int e  = l & 31;
        const int hi = l >> 5;
        const int eC  = (e < 15) ? e : 14;
        const int eC3 = (e < 6)  ? e : 5;

        f16x8 bf1a, bf1b, bf2;
        #pragma unroll
        for (int m = 0; m < 8; ++m) {
            int ka  = hi * 8 + m;
            int kb_ = 16 + ka;
            float wa = frw2[ka * 15 + eC];
            float wb = (kb_ < 30) ? frw2[kb_ * 15 + eC] : frb2[eC];
            float w3 = (ka  < 15) ? frw3[ka * 6 + eC3]  : frb3[eC3];
            bf1a[m] = (e < 15)              ? (f16)wa : (f16)0.f;
            bf1b[m] = (e < 15 && kb_ < 31)  ? (f16)wb : (f16)0.f;
            bf2[m]  = (e < 6)               ? (f16)w3 : (f16)0.f;
        }
        f32x16 cz;
        #pragma unroll
        for (int r = 0; r < 16; ++r) cz[r] = 0.f;

        for (int base = wv; base < 50; base += 8) {
            const int iA = base, iB = base + 50;
            const char* prpA = PrB + iA * 80 + ((hi ^ ((iA >> 3) & 1)) * 16);
            const char* prpB = PrB + iB * 80 + ((hi ^ ((iB >> 3) & 1)) * 16);
            f16x8 praA = *(const f16x8*)prpA;
            f16x8 prbA = *(const f16x8*)(prpA + 32);
            f16x8 praB = *(const f16x8*)prpB;
            f16x8 prbB = *(const f16x8*)(prpB + 32);
            float2 rA[2], rB[2];
            rA[0].x=0.f; rA[0].y=0.f; rA[1].x=0.f; rA[1].y=0.f;
            rB[0].x=0.f; rB[0].y=0.f; rB[1].x=0.f; rB[1].y=0.f;

            int jA = iA + 1 + e; if (jA >= 100) jA -= 100;
            int jB = iB + 1 + e; if (jB >= 100) jB -= 100;
            #pragma unroll
            for (int tb = 0; tb < 4; ++tb) {
                const char* pspA = PsB + jA * 80 + ((hi ^ ((jA >> 3) & 1)) * 16);
                const char* pspB = PsB + jB * 80 + ((hi ^ ((jB >> 3) & 1)) * 16);
                f16x8 psaA = *(const f16x8*)pspA;
                f16x8 psbA = *(const f16x8*)(pspA + 32);
                f16x8 psaB = *(const f16x8*)pspB;
                f16x8 psbB = *(const f16x8*)(pspB + 32);

                f16x8 h1aA = praA + psaA, h1bA = prbA + psbA;
                f16x8 h1aB = praB + psaB, h1bB = prbB + psbB;
                #pragma unroll
                for (int m = 0; m < 8; ++m) {
                    h1aA[m] = (h1aA[m] > (f16)0.f) ? h1aA[m] : (f16)0.f;
                    h1bA[m] = (h1bA[m] > (f16)0.f) ? h1bA[m] : (f16)0.f;
                    h1aB[m] = (h1aB[m] > (f16)0.f) ? h1aB[m] : (f16)0.f;
                    h1bB[m] = (h1bB[m] > (f16)0.f) ? h1bB[m] : (f16)0.f;
                }
                f32x16 c1A = __builtin_amdgcn_mfma_f32_32x32x16_f16(bf1a, h1aA, cz, 0, 0, 0);
                f32x16 c1B = __builtin_amdgcn_mfma_f32_32x32x16_f16(bf1a, h1aB, cz, 0, 0, 0);
                c1A = __builtin_amdgcn_mfma_f32_32x32x16_f16(bf1b, h1bA, c1A, 0, 0, 0);
                c1B = __builtin_amdgcn_mfma_f32_32x32x16_f16(bf1b, h1bB, c1B, 0, 0, 0);

                float v7A = hi ? 1.0f : fmaxf(c1A[7], 0.f);
                float v7B = hi ? 1.0f : fmaxf(c1B[7], 0.f);
                int pw0A = __builtin_bit_cast(int, __builtin_amdgcn_cvt_pkrtz(fmaxf(c1A[0], 0.f), fmaxf(c1A[1], 0.f)));
                int pw1A = __builtin_bit_cast(int, __builtin_amdgcn_cvt_pkrtz(fmaxf(c1A[2], 0.f), fmaxf(c1A[3], 0.f)));
                int pw2A = __builtin_bit_cast(int, __builtin_amdgcn_cvt_pkrtz(fmaxf(c1A[4], 0.f), fmaxf(c1A[5], 0.f)));
                int pw3A = __builtin_bit_cast(int, __builtin_amdgcn_cvt_pkrtz(fmaxf(c1A[6], 0.f), v7A));
                int pw0B = __builtin_bit_cast(int, __builtin_amdgcn_cvt_pkrtz(fmaxf(c1B[0], 0.f), fmaxf(c1B[1], 0.f)));
                int pw1B = __builtin_bit_cast(int, __builtin_amdgcn_cvt_pkrtz(fmaxf(c1B[2], 0.f), fmaxf(c1B[3], 0.f)));
                int pw2B = __builtin_bit_cast(int, __builtin_amdgcn_cvt_pkrtz(fmaxf(c1B[4], 0.f), fmaxf(c1B[5], 0.f)));
                int pw3B = __builtin_bit_cast(int, __builtin_amdgcn_cvt_pkrtz(fmaxf(c1B[6], 0.f), v7B));

                int r0A = __shfl_xor(hi ? pw0A : pw2A, 32);
                int r1A = __shfl_xor(hi ? pw1A : pw3A, 32);
                int r0B = __shfl_xor(hi ? pw0B : pw2B, 32);
                int r1B = __shfl_xor(hi ? pw1B : pw3B, 32);
                union { int w[4]; f16x8 v; } a2A, a2B;
                a2A.w[0] = hi ? r0A  : pw0A;  a2A.w[1] = hi ? r1A  : pw1A;
                a2A.w[2] = hi ? pw2A : r0A;   a2A.w[3] = hi ? pw3A : r1A;
                a2B.w[0] = hi ? r0B  : pw0B;  a2B.w[1] = hi ? r1B  : pw1B;
                a2B.w[2] = hi ? pw2B : r0B;   a2B.w[3] = hi ? pw3B : r1B;

                f32x16 c2A = __builtin_amdgcn_mfma_f32_32x32x16_f16(a2A.v, bf2, cz, 0, 0, 0);
                f32x16 c2B = __builtin_amdgcn_mfma_f32_32x32x16_f16(a2B.v, bf2, cz, 0, 0, 0);

                if (tb < 3) {
                    #pragma unroll
                    for (int p = 0; p < 8; ++p) {
                        rA[p & 1].x += fmaxf(c2A[2 * p],     0.f);
                        rA[p & 1].y += fmaxf(c2A[2 * p + 1], 0.f);
                        rB[p & 1].x += fmaxf(c2B[2 * p],     0.f);
                        rB[p & 1].y += fmaxf(c2B[2 * p + 1], 0.f);
                    }
                } else if (hi == 0) {
                    rA[0].x += fmaxf(c2A[0], 0.f);
                    rA[0].y += fmaxf(c2A[1], 0.f);
                    rA[1].x += fmaxf(c2A[2], 0.f);
                    rB[0].x += fmaxf(c2B[0], 0.f);
                    rB[0].y += fmaxf(c2B[1], 0.f);
                    rB[1].x += fmaxf(c2B[2], 0.f);
                }
                jA += 32; if (jA >= 100) jA -= 100;
                jB += 32; if (jB >= 100) jB -= 100;
            }
            float sA = rA[0].x + rA[0].y + rA[1].x + rA[1].y;
            float sB = rB[0].x + rB[0].y + rB[1].x + rB[1].y;
            sA += __shfl_xor(sA, 32);
            sB += __shfl_xor(sB, 32);
            if (hi == 0 && e < 6) {
                aggF[iA * 8 + e] = sA;
                aggF[iB * 8 + e] = sB;
            }
        }
    }
    __syncthreads();

    // ---- fo + fc (R9-verified) ----
    for (int idx = tid; idx < NCONST * 45; idx += BLK) {
        int n = idx / 45, o = idx - n * 45;
        float acc = fob1[o];
        const float4* xv = (const float4*)(&xbn[n][0]);
        #pragma unroll
        for (int q = 0; q < 4; ++q) {
            float4 xq = xv[q];
            acc = fmaf(xq.x, fow1[(4 * q + 0) * 45 + o], acc);
            acc = fmaf(xq.y, fow1[(4 * q + 1) * 45 + o], acc);
            acc = fmaf(xq.z, fow1[(4 * q + 2) * 45 + o], acc);
            acc = fmaf(xq.w, fow1[(4 * q + 3) * 45 + o], acc);
        }
        const float4 a0 = *(const float4*)(&aggF[n * 8]);
        const float2 a1 = *(const float2*)(&aggF[n * 8 + 4]);
        acc = fmaf(a0.x, fow1[16 * 45 + o], acc);
        acc = fmaf(a0.y, fow1[17 * 45 + o], acc);
        acc = fmaf(a0.z, fow1[18 * 45 + o], acc);
        acc = fmaf(a0.w, fow1[19 * 45 + o], acc);
        acc = fmaf(a1.x, fow1[20 * 45 + o], acc);
        acc = fmaf(a1.y, fow1[21 * 45 + o], acc);
        foh1[n][o] = fmaxf(acc, 0.f);
    }
    __syncthreads();
    for (int idx = tid; idx < NCONST * 22; idx += BLK) {
        int n = idx / 22, o = idx - n * 22;
        float acc = fob2[o];
        const float4* hv = (const float4*)(&foh1[n][0]);
        #pragma unroll
        for (int q = 0; q < 11; ++q) {
            float4 h4 = hv[q];
            acc = fmaf(h4.x, fow2[(4 * q + 0) * 22 + o], acc);
            acc = fmaf(h4.y, fow2[(4 * q + 1) * 22 + o], acc);
            acc = fmaf(h4.z, fow2[(4 * q + 2) * 22 + o], acc);
            acc = fmaf(h4.w, fow2[(4 * q + 3) * 22 + o], acc);
        }
        acc = fmaf(foh1[n][44], fow2[44 * 22 + o], acc);
        foh2[n][o] = fmaxf(acc, 0.f);
    }
    __syncthreads();
    for (int idx = tid; idx < NCONST * 6; idx += BLK) {
        int n = idx / 6, c = idx - n * 6;
        float acc = fob3[c];
        const float4* hv = (const float4*)(&foh2[n][0]);
        #pragma unroll
        for (int q = 0; q < 5; ++q) {
            float4 h4 = hv[q];
            acc = fmaf(h4.x, fow3[(4 * q + 0) * 6 + c], acc);
            acc = fmaf(h4.y, fow3[(4 * q + 1) * 6 + c], acc);
            acc = fmaf(h4.z, fow3[(4 * q + 2) * 6 + c], acc);
            acc = fmaf(h4.w, fow3[(4 * q + 3) * 6 + c], acc);
        }
        acc = fmaf(foh2[n][20], fow3[20 * 6 + c], acc);
        acc = fmaf(foh2[n][21], fow3[21 * 6 + c], acc);
        atomicAdd(&fcin[c], fmaxf(acc, 0.f));
    }
    __syncthreads();
    if (tid < 48) {
        float acc = fcb1[tid];
        #pragma unroll
        for (int k = 0; k < 6; ++k) acc = fmaf(fcin[k], fcw1[k * 48 + tid], acc);
        hfc[tid] = fmaxf(acc, 0.f);
    }
    __syncthreads();
    if (tid < 5) {
        float acc = fcb2[tid];
        #pragma unroll
        for (int k = 0; k < 48; ++k) acc = fmaf(hfc[k], fcw2[k * 5 + tid], acc);
        logits[tid] = acc;
    }
    __syncthreads();
    if (tid == 0) {
        float m = logits[0];
        #pragma unroll
        for (int c = 1; c < 5; ++c) m = fmaxf(m, logits[c]);
        float ex[5], sum = 0.f;
        #pragma unroll
        for (int c = 0; c < 5; ++c) { ex[c] = __expf(logits[c] - m); sum += ex[c]; }
        float inv = 1.f / sum;
        #pragma unroll
        for (int c = 0; c < 5; ++c) out[(size_t)b * 5 + c] = ex[c] * inv;
    }
}

// ===================== ABLATION PROBES (write only to ws) =====================
// V1: proj only. V0: proj + exact-R9 1-chain edge. V2: V0 minus shfl
// redistribute. V3: V0 minus everything after pack. Deterministic; outputs go
// to disjoint ws regions; per-dispatch dur from rocprof = phase decomposition.
template<int V>
__global__ __launch_bounds__(512, 4) void abl_probe(
    const float* __restrict__ x,
    const float* __restrict__ bn_g, const float* __restrict__ bn_b,
    const float* __restrict__ bn_m, const float* __restrict__ bn_v,
    const float* __restrict__ frw1, const float* __restrict__ frb1,
    const float* __restrict__ frw2, const float* __restrict__ frb2,
    const float* __restrict__ frw3, const float* __restrict__ frb3,
    float* __restrict__ ws)
{
    __shared__ float xbn[NCONST][NF];
    __shared__ char P[16000];
    char* const PrB = P;
    char* const PsB = P + 8000;

    const int b   = blockIdx.x;
    const int tid = threadIdx.x;
    const float* xb = x + (size_t)b * (NCONST * NF);

    for (int idx = tid; idx < NCONST * NF; idx += BLK) {
        int f = idx & 15;
        float sc = rsqrtf(bn_v[f] + 1e-3f) * bn_g[f];
        xbn[idx >> 4][f] = (xb[idx] - bn_m[f]) * sc + bn_b[f];
    }
    __syncthreads();
    for (int idx = tid; idx < 1600; idx += BLK) {
        int n = idx >> 4, rem = idx & 15, sel = rem >> 3, oq = rem & 7, o0 = oq * 4;
        float xs[16];
        {
            const float4* xv = (const float4*)(&xbn[n][0]);
            float4 x0 = xv[0], x1 = xv[1], x2 = xv[2], x3 = xv[3];
            xs[0]=x0.x; xs[1]=x0.y; xs[2]=x0.z; xs[3]=x0.w;
            xs[4]=x1.x; xs[5]=x1.y; xs[6]=x1.z; xs[7]=x1.w;
            xs[8]=x2.x; xs[9]=x2.y; xs[10]=x2.z; xs[11]=x2.w;
            xs[12]=x3.x; xs[13]=x3.y; xs[14]=x3.z; xs[15]=x3.w;
        }
        float acc0 = (!sel) ? frb1[o0 + 0] : 0.f;
        float acc1 = (!sel) ? frb1[o0 + 1] : 0.f;
        float acc2 = (!sel && oq < 7) ? frb1[o0 + 2] : 0.f;
        float acc3 = (!sel && oq < 7) ? frb1[o0 + 3] : 0.f;
        const float* wbase = frw1 + sel * 16 * 30;
        const int wcol2 = (oq < 7) ? o0 + 2 : 28;
        #pragma unroll
        for (int f = 0; f < 16; ++f) {
            const float* wr = wbase + f * 30;
            float2 wa = *(const float2*)(wr + o0);
            float2 wb = *(const float2*)(wr + wcol2);
            acc0 = fmaf(xs[f], wa.x, acc0);
            acc1 = fmaf(xs[f], wa.y, acc1);
            acc2 = fmaf(xs[f], wb.x, acc2);
            acc3 = fmaf(xs[f], wb.y, acc3);
        }
        f16x4 hv;
        hv[0] = (f16)acc0;
        hv[1] = (f16)acc1;
        hv[2] = (oq < 7) ? (f16)acc2 : (sel ? (f16)0.f : (f16)1.f);
        hv[3] = (oq < 7) ? (f16)acc3 : (f16)0.f;
        int slot = oq >> 1;
        int sw = (slot & 2) | ((slot ^ (n >> 3)) & 1);
        *(f16x4*)((sel ? PsB : PrB) + n * 80 + sw * 16 + (oq & 1) * 8) = hv;
    }
    __syncthreads();

    if constexpr (V == 1) {
        if (tid < 500) {
            f16x8 a = *(const f16x8*)(P + tid * 32);
            f16x8 c = *(const f16x8*)(P + tid * 32 + 16);
            float s = 0.f;
            #pragma unroll
            for (int m = 0; m < 8; ++m) s += (float)a[m] + (float)c[m];
            ws[(size_t)b * 512 + tid] = s;
        }
        return;
    } else {
        const int l  = tid & 63;
        const int wv = tid >> 6;
        const int e  = l & 31;
        const int hi = l >> 5;
        const int eC  = (e < 15) ? e : 14;
        const int eC3 = (e < 6)  ? e : 5;
        f16x8 bf1a, bf1b, bf2;
        #pragma unroll
        for (int m = 0; m < 8; ++m) {
            int ka  = hi * 8 + m;
            int kb_ = 16 + ka;
            float wa = frw2[ka * 15 + eC];
            float wb = (kb_ < 30) ? frw2[kb_ * 15 + eC] : frb2[eC];
            float w3 = (ka  < 15) ? frw3[ka * 6 + eC3]  : frb3[eC3];
            bf1a[m] = (e < 15)              ? (f16)wa : (f16)0.f;
            bf1b[m] = (e < 15 && kb_ < 31)  ? (f16)wb : (f16)0.f;
            bf2[m]  = (e < 6)               ? (f16)w3 : (f16)0.f;
        }
        f32x16 cz;
        #pragma unroll
        for (int r = 0; r < 16; ++r) cz[r] = 0.f;

        for (int i = wv; i < NCONST; i += 8) {
            const char* prp = PrB + i * 80 + ((hi ^ ((i >> 3) & 1)) * 16);
            f16x8 pra = *(const f16x8*)prp;
            f16x8 prb = *(const f16x8*)(prp + 32);
            float2 r2[2];
            r2[0].x = 0.f; r2[0].y = 0.f; r2[1].x = 0.f; r2[1].y = 0.f;
            int ri = 0;
            int j = i + 1 + e; if (j >= 100) j -= 100;
            #pragma unroll
            for (int tb = 0; tb < 4; ++tb) {
                const char* psp = PsB + j * 80 + ((hi ^ ((j >> 3) & 1)) * 16);
                f16x8 psa = *(const f16x8*)psp;
                f16x8 psb = *(const f16x8*)(psp + 32);
                f16x8 h1a = pra + psa;
                f16x8 h1b = prb + psb;
                #pragma unroll
                for (int m = 0; m < 8; ++m) {
                    h1a[m] = (h1a[m] > (f16)0.f) ? h1a[m] : (f16)0.f;
                    h1b[m] = (h1b[m] > (f16)0.f) ? h1b[m] : (f16)0.f;
                }
                f32x16 c1 = __builtin_amdgcn_mfma_f32_32x32x16_f16(bf1a, h1a, cz, 0, 0, 0);
                c1 = __builtin_amdgcn_mfma_f32_32x32x16_f16(bf1b, h1b, c1, 0, 0, 0);
                float v7 = hi ? 1.0f : fmaxf(c1[7], 0.f);
                int pw0 = __builtin_bit_cast(int, __builtin_amdgcn_cvt_pkrtz(fmaxf(c1[0], 0.f), fmaxf(c1[1], 0.f)));
                int pw1 = __builtin_bit_cast(int, __builtin_amdgcn_cvt_pkrtz(fmaxf(c1[2], 0.f), fmaxf(c1[3], 0.f)));
                int pw2 = __builtin_bit_cast(int, __builtin_amdgcn_cvt_pkrtz(fmaxf(c1[4], 0.f), fmaxf(c1[5], 0.f)));
                int pw3 = __builtin_bit_cast(int, __builtin_amdgcn_cvt_pkrtz(fmaxf(c1[6], 0.f), v7));

                if constexpr (V == 3) {
                    ri += pw0 + pw1 + pw2 + pw3;   // keep pack live; skip back half
                } else {
                    union { int w[4]; f16x8 v; } a2;
                    if constexpr (V == 2) {
                        a2.w[0] = pw0; a2.w[1] = pw1; a2.w[2] = pw2; a2.w[3] = pw3;
                    } else {
                        int r0 = __shfl_xor(hi ? pw0 : pw2, 32);
                        int r1 = __shfl_xor(hi ? pw1 : pw3, 32);
                        a2.w[0] = hi ? r0  : pw0;
                        a2.w[1] = hi ? r1  : pw1;
                        a2.w[2] = hi ? pw2 : r0;
                        a2.w[3] = hi ? pw3 : r1;
                    }
                    f32x16 c2 = __builtin_amdgcn_mfma_f32_32x32x16_f16(a2.v, bf2, cz, 0, 0, 0);
                    if (tb < 3) {
                        #pragma unroll
                        for (int p = 0; p < 8; ++p) {
                            r2[p & 1].x += fmaxf(c2[2 * p],     0.f);
                            r2[p & 1].y += fmaxf(c2[2 * p + 1], 0.f);
                        }
                    } else if (hi == 0) {
                        r2[0].x += fmaxf(c2[0], 0.f);
                        r2[0].y += fmaxf(c2[1], 0.f);
                        r2[1].x += fmaxf(c2[2], 0.f);
                    }
                }
                j += 32; if (j >= 100) j -= 100;
            }
            float s = (V == 3) ? (float)ri
                               : (r2[0].x + r2[0].y + r2[1].x + r2[1].y);
            s += __shfl_xor(s, 32);
            if (hi == 0 && e < 6)
                ws[(size_t)b * 800 + i * 8 + e] = s;
        }
    }
}

extern "C" void kernel_launch(void* const* d_in, const int* in_sizes, int n_in,
                              void* d_out, int out_size, void* d_ws, size_t ws_size,
                              hipStream_t stream) {
    const float* x     = (const float*)d_in[0];
    const float* bn_g  = (const float*)d_in[1];
    const float* bn_b  = (const float*)d_in[2];
    const float* bn_m  = (const float*)d_in[3];
    const float* bn_v  = (const float*)d_in[4];
    const float* frw1  = (const float*)d_in[5];
    const float* frb1  = (const float*)d_in[6];
    const float* frw2  = (const float*)d_in[7];
    const float* frb2  = (const float*)d_in[8];
    const float* frw3  = (const float*)d_in[9];
    const float* frb3  = (const float*)d_in[10];
    const float* fow1  = (const float*)d_in[11];
    const float* fob1  = (const float*)d_in[12];
    const float* fow2  = (const float*)d_in[13];
    const float* fob2  = (const float*)d_in[14];
    const float* fow3  = (const float*)d_in[15];
    const float* fob3  = (const float*)d_in[16];
    const float* fcw1  = (const float*)d_in[17];
    const float* fcb1  = (const float*)d_in[18];
    const float* fcw2  = (const float*)d_in[19];
    const float* fcb2  = (const float*)d_in[20];

    const int B = in_sizes[0] / (NCONST * NF);   // 512
    float* wsf = (float*)d_ws;

    convint_fused<<<dim3(B), dim3(BLK), 0, stream>>>(
        x, bn_g, bn_b, bn_m, bn_v,
        frw1, frb1, frw2, frb2, frw3, frb3,
        fow1, fob1, fow2, fob2, fow3, fob3,
        fcw1, fcb1, fcw2, fcb2,
        (float*)d_out);

    abl_probe<1><<<dim3(B), dim3(BLK), 0, stream>>>(
        x, bn_g, bn_b, bn_m, bn_v, frw1, frb1, frw2, frb2, frw3, frb3,
        wsf + 0 * 524288);
    abl_probe<0><<<dim3(B), dim3(BLK), 0, stream>>>(
        x, bn_g, bn_b, bn_m, bn_v, frw1, frb1, frw2, frb2, frw3, frb3,
        wsf + 1 * 524288);
    abl_probe<2><<<dim3(B), dim3(BLK), 0, stream>>>(
        x, bn_g, bn_b, bn_m, bn_v, frw1, frb1, frw2, frb2, frw3, frb3,
        wsf + 2 * 524288);
    abl_probe<3><<<dim3(B), dim3(BLK), 0, stream>>>(
        x, bn_g, bn_b, bn_m, bn_v, frw1, frb1, frw2, frb2, frw3, frb3,
        wsf + 3 * 524288);
}

// Round 12
// 61.961 us; speedup vs baseline: 3.4386x; 3.4386x over previous
//
#include <hip/hip_runtime.h>
#include <math.h>

#define NCONST 100
#define NF     16
#define BLK    512

typedef _Float16 f16;
typedef _Float16 f16x8 __attribute__((ext_vector_type(8)));
typedef _Float16 f16x4 __attribute__((ext_vector_type(4)));
typedef float    f32x16 __attribute__((ext_vector_type(16)));

// One block per batch element, 512 threads (8 waves). VALU-issue-bound (R11
// analysis: 800 tiles/CU x ~73 VALU x 2cy == measured 47us edge). This round
// cuts per-tile VALU:
//  - W2 columns pre-permuted (swap o2 4-7 <-> 8-11) so D1 regs 0..7 ARE the
//    MFMA2 fragment (k2 = hi*8+m in order) -> no shfl redistribute at all.
//  - MFMA2 transposed: D2 = W3^T(rows=6 outputs) x h2(cols=32 edges); rows
//    6..15 exactly zero -> accumulate = 4 fmax + 4 add per tile (was 32).
//    Sum over edges via one 5-stage butterfly per receiver.
//  - b2 folded at k=30 (Pr half-30 == 1), b3 folded at k2=15 (a2[7]=1 on hi).
// launch_bounds(512,4); spill tripwire = WRITE_SIZE >> 24KB (R3/R11 lesson).
__global__ __launch_bounds__(BLK, 4) void convint_fused(
    const float* __restrict__ x,
    const float* __restrict__ bn_g, const float* __restrict__ bn_b,
    const float* __restrict__ bn_m, const float* __restrict__ bn_v,
    const float* __restrict__ frw1, const float* __restrict__ frb1,
    const float* __restrict__ frw2, const float* __restrict__ frb2,
    const float* __restrict__ frw3, const float* __restrict__ frb3,
    const float* __restrict__ fow1, const float* __restrict__ fob1,
    const float* __restrict__ fow2, const float* __restrict__ fob2,
    const float* __restrict__ fow3, const float* __restrict__ fob3,
    const float* __restrict__ fcw1, const float* __restrict__ fcb1,
    const float* __restrict__ fcw2, const float* __restrict__ fcb2,
    float* __restrict__ out)
{
    __shared__ float xbn[NCONST][NF];
    __shared__ float upool[7200];
    __shared__ float aggF[NCONST * 8];
    __shared__ float fcin[8];
    __shared__ float hfc[48];
    __shared__ float logits[8];

    char* const PrB = (char*)upool;           // 8000 B, swizzled 16B slots
    char* const PsB = PrB + 8000;             // 8000 B
    float (*const foh1)[48] = (float (*)[48])upool;
    float (*const foh2)[24] = (float (*)[24])(upool + 4800);

    const int b   = blockIdx.x;
    const int tid = threadIdx.x;
    const float* xb = x + (size_t)b * (NCONST * NF);

    for (int idx = tid; idx < NCONST * NF; idx += BLK) {
        int f = idx & 15;
        float sc = rsqrtf(bn_v[f] + 1e-3f) * bn_g[f];
        xbn[idx >> 4][f] = (xb[idx] - bn_m[f]) * sc + bn_b[f];
    }
    if (tid < 8) fcin[tid] = 0.f;
    __syncthreads();

    // ---- proj (R9-verified): Pr/Ps f16 rows of 40 halves, swizzled ----
    for (int idx = tid; idx < 1600; idx += BLK) {
        int n   = idx >> 4;
        int rem = idx & 15;
        int sel = rem >> 3;
        int oq  = rem & 7;
        int o0  = oq * 4;
        float xs[16];
        {
            const float4* xv = (const float4*)(&xbn[n][0]);
            float4 x0 = xv[0], x1 = xv[1], x2 = xv[2], x3 = xv[3];
            xs[0]=x0.x; xs[1]=x0.y; xs[2]=x0.z; xs[3]=x0.w;
            xs[4]=x1.x; xs[5]=x1.y; xs[6]=x1.z; xs[7]=x1.w;
            xs[8]=x2.x; xs[9]=x2.y; xs[10]=x2.z; xs[11]=x2.w;
            xs[12]=x3.x; xs[13]=x3.y; xs[14]=x3.z; xs[15]=x3.w;
        }
        float acc0 = (!sel) ? frb1[o0 + 0] : 0.f;
        float acc1 = (!sel) ? frb1[o0 + 1] : 0.f;
        float acc2 = (!sel && oq < 7) ? frb1[o0 + 2] : 0.f;
        float acc3 = (!sel && oq < 7) ? frb1[o0 + 3] : 0.f;
        const float* wbase = frw1 + sel * 16 * 30;
        const int wcol2 = (oq < 7) ? o0 + 2 : 28;
        #pragma unroll
        for (int f = 0; f < 16; ++f) {
            const float* wr = wbase + f * 30;
            float2 wa = *(const float2*)(wr + o0);
            float2 wb = *(const float2*)(wr + wcol2);
            acc0 = fmaf(xs[f], wa.x, acc0);
            acc1 = fmaf(xs[f], wa.y, acc1);
            acc2 = fmaf(xs[f], wb.x, acc2);
            acc3 = fmaf(xs[f], wb.y, acc3);
        }
        f16x4 hv;
        hv[0] = (f16)acc0;
        hv[1] = (f16)acc1;
        hv[2] = (oq < 7) ? (f16)acc2 : (sel ? (f16)0.f : (f16)1.f);  // half30: bias carrier
        hv[3] = (oq < 7) ? (f16)acc3 : (f16)0.f;                     // half31: 0 (k-pad)
        int slot = oq >> 1;
        int sw = (slot & 2) | ((slot ^ (n >> 3)) & 1);
        *(f16x4*)((sel ? PsB : PrB) + n * 80 + sw * 16 + (oq & 1) * 8) = hv;
    }
    __syncthreads();

    // ---- edge phase (perm'd W2, transposed MFMA2) ----
    {
        const int l  = tid & 63;
        const int wv = tid >> 6;
        const int e  = l & 31;
        const int hi = l >> 5;

        // permuted W2 column for this A-row: kappa swaps [4..7] <-> [8..11]
        const int o2p = (e >= 4 && e < 12) ? (e ^ 12) : e;
        const bool o2v = (o2p < 15);
        const int  o2c = o2v ? o2p : 0;
        const bool o3v = (e < 6);
        const int  o3c = o3v ? e : 0;

        f16x8 bf1a, bf1b, bf2p;
        #pragma unroll
        for (int m = 0; m < 8; ++m) {
            int ka  = hi * 8 + m;          // 0..15
            int kb_ = 16 + ka;             // 16..31
            bf1a[m] = o2v ? (f16)frw2[ka * 15 + o2c] : (f16)0.f;
            f16 wb = (f16)0.f;
            if (o2v) {
                if (kb_ < 30)       wb = (f16)frw2[kb_ * 15 + o2c];
                else if (kb_ == 30) wb = (f16)frb2[o2c];         // b2 rides k=30
            }
            bf1b[m] = wb;
            f16 w3 = (f16)0.f;
            if (o3v) {
                if (ka < 15)       w3 = (f16)frw3[ka * 6 + o3c];
                else               w3 = (f16)frb3[o3c];          // b3 rides k2=15
            }
            bf2p[m] = w3;
        }
        f32x16 cz;
        #pragma unroll
        for (int r = 0; r < 16; ++r) cz[r] = 0.f;
        const float gtail = (e < 3) ? 1.f : 0.f;   // tb=3 valid senders 96..98

        for (int i = wv; i < NCONST; i += 8) {
            const char* prp = PrB + i * 80 + ((hi ^ ((i >> 3) & 1)) * 16);
            f16x8 pra = *(const f16x8*)prp;
            f16x8 prb = *(const f16x8*)(prp + 32);
            float rc0 = 0.f, rc1 = 0.f, rc2 = 0.f, rc3 = 0.f;

            int j = i + 1 + e; if (j >= 100) j -= 100;
            #pragma unroll
            for (int tb = 0; tb < 4; ++tb) {
                const char* psp = PsB + j * 80 + ((hi ^ ((j >> 3) & 1)) * 16);
                f16x8 psa = *(const f16x8*)psp;
                f16x8 psb = *(const f16x8*)(psp + 32);
                f16x8 h1a = pra + psa;
                f16x8 h1b = prb + psb;
                #pragma unroll
                for (int m = 0; m < 8; ++m) {
                    h1a[m] = (h1a[m] > (f16)0.f) ? h1a[m] : (f16)0.f;
                    h1b[m] = (h1b[m] > (f16)0.f) ? h1b[m] : (f16)0.f;
                }
                // MFMA1: D1[o2-slot][edge]; perm makes regs 0..7 = h2[hi*8+m]
                f32x16 c1 = __builtin_amdgcn_mfma_f32_32x32x16_f16(bf1a, h1a, cz, 0, 0, 0);
                c1 = __builtin_amdgcn_mfma_f32_32x32x16_f16(bf1b, h1b, c1, 0, 0, 0);

                // pack + relu (RTZ commutes with relu); regs ARE the fragment
                union { int w[4]; f16x8 v; } a2;
                a2.w[0] = __builtin_bit_cast(int, __builtin_amdgcn_cvt_pkrtz(c1[0], c1[1]));
                a2.w[1] = __builtin_bit_cast(int, __builtin_amdgcn_cvt_pkrtz(c1[2], c1[3]));
                a2.w[2] = __builtin_bit_cast(int, __builtin_amdgcn_cvt_pkrtz(c1[4], c1[5]));
                a2.w[3] = __builtin_bit_cast(int, __builtin_amdgcn_cvt_pkrtz(c1[6], c1[7]));
                #pragma unroll
                for (int m = 0; m < 8; ++m)
                    a2.v[m] = (a2.v[m] > (f16)0.f) ? a2.v[m] : (f16)0.f;
                a2.v[7] = hi ? (f16)1.f : a2.v[7];   // k2=15 bias slot

                // MFMA2 transposed: D2[o3-rows][edge-cols]; rows 6..15 == 0
                f32x16 c2 = __builtin_amdgcn_mfma_f32_32x32x16_f16(bf2p, a2.v, cz, 0, 0, 0);

                if (tb < 3) {
                    rc0 += fmaxf(c2[0], 0.f);
                    rc1 += fmaxf(c2[1], 0.f);
                    rc2 += fmaxf(c2[2], 0.f);
                    rc3 += fmaxf(c2[3], 0.f);
                } else {
                    rc0 = fmaf(gtail, fmaxf(c2[0], 0.f), rc0);
                    rc1 = fmaf(gtail, fmaxf(c2[1], 0.f), rc1);
                    rc2 = fmaf(gtail, fmaxf(c2[2], 0.f), rc2);
                    rc3 = fmaf(gtail, fmaxf(c2[3], 0.f), rc3);
                }
                j += 32; if (j >= 100) j -= 100;
            }
            // sum over 32 edge-lanes (stay within each 32-half)
            #pragma unroll
            for (int mk = 1; mk <= 16; mk <<= 1) {
                rc0 += __shfl_xor(rc0, mk);
                rc1 += __shfl_xor(rc1, mk);
                rc2 += __shfl_xor(rc2, mk);
                rc3 += __shfl_xor(rc3, mk);
            }
            if (l == 0) {
                float4 v; v.x = rc0; v.y = rc1; v.z = rc2; v.w = rc3;
                *(float4*)&aggF[i * 8] = v;            // o3 0..3
            } else if (l == 32) {
                float2 v; v.x = rc0; v.y = rc1;
                *(float2*)&aggF[i * 8 + 4] = v;        // o3 4..5
            }
        }
    }
    __syncthreads();

    // ---- fo + fc (R9-verified) ----
    for (int idx = tid; idx < NCONST * 45; idx += BLK) {
        int n = idx / 45, o = idx - n * 45;
        float acc = fob1[o];
        const float4* xv = (const float4*)(&xbn[n][0]);
        #pragma unroll
        for (int q = 0; q < 4; ++q) {
            float4 xq = xv[q];
            acc = fmaf(xq.x, fow1[(4 * q + 0) * 45 + o], acc);
            acc = fmaf(xq.y, fow1[(4 * q + 1) * 45 + o], acc);
            acc = fmaf(xq.z, fow1[(4 * q + 2) * 45 + o], acc);
            acc = fmaf(xq.w, fow1[(4 * q + 3) * 45 + o], acc);
        }
        const float4 a0 = *(const float4*)(&aggF[n * 8]);
        const float2 a1 = *(const float2*)(&aggF[n * 8 + 4]);
        acc = fmaf(a0.x, fow1[16 * 45 + o], acc);
        acc = fmaf(a0.y, fow1[17 * 45 + o], acc);
        acc = fmaf(a0.z, fow1[18 * 45 + o], acc);
        acc = fmaf(a0.w, fow1[19 * 45 + o], acc);
        acc = fmaf(a1.x, fow1[20 * 45 + o], acc);
        acc = fmaf(a1.y, fow1[21 * 45 + o], acc);
        foh1[n][o] = fmaxf(acc, 0.f);
    }
    __syncthreads();
    for (int idx = tid; idx < NCONST * 22; idx += BLK) {
        int n = idx / 22, o = idx - n * 22;
        float acc = fob2[o];
        const float4* hv = (const float4*)(&foh1[n][0]);
        #pragma unroll
        for (int q = 0; q < 11; ++q) {
            float4 h4 = hv[q];
            acc = fmaf(h4.x, fow2[(4 * q + 0) * 22 + o], acc);
            acc = fmaf(h4.y, fow2[(4 * q + 1) * 22 + o], acc);
            acc = fmaf(h4.z, fow2[(4 * q + 2) * 22 + o], acc);
            acc = fmaf(h4.w, fow2[(4 * q + 3) * 22 + o], acc);
        }
        acc = fmaf(foh1[n][44], fow2[44 * 22 + o], acc);
        foh2[n][o] = fmaxf(acc, 0.f);
    }
    __syncthreads();
    for (int idx = tid; idx < NCONST * 6; idx += BLK) {
        int n = idx / 6, c = idx - n * 6;
        float acc = fob3[c];
        const float4* hv = (const float4*)(&foh2[n][0]);
        #pragma unroll
        for (int q = 0; q < 5; ++q) {
            float4 h4 = hv[q];
            acc = fmaf(h4.x, fow3[(4 * q + 0) * 6 + c], acc);
            acc = fmaf(h4.y, fow3[(4 * q + 1) * 6 + c], acc);
            acc = fmaf(h4.z, fow3[(4 * q + 2) * 6 + c], acc);
            acc = fmaf(h4.w, fow3[(4 * q + 3) * 6 + c], acc);
        }
        acc = fmaf(foh2[n][20], fow3[20 * 6 + c], acc);
        acc = fmaf(foh2[n][21], fow3[21 * 6 + c], acc);
        atomicAdd(&fcin[c], fmaxf(acc, 0.f));
    }
    __syncthreads();
    if (tid < 48) {
        float acc = fcb1[tid];
        #pragma unroll
        for (int k = 0; k < 6; ++k) acc = fmaf(fcin[k], fcw1[k * 48 + tid], acc);
        hfc[tid] = fmaxf(acc, 0.f);
    }
    __syncthreads();
    if (tid < 5) {
        float acc = fcb2[tid];
        #pragma unroll
        for (int k = 0; k < 48; ++k) acc = fmaf(hfc[k], fcw2[k * 5 + tid], acc);
        logits[tid] = acc;
    }
    __syncthreads();
    if (tid == 0) {
        float m = logits[0];
        #pragma unroll
        for (int c = 1; c < 5; ++c) m = fmaxf(m, logits[c]);
        float ex[5], sum = 0.f;
        #pragma unroll
        for (int c = 0; c < 5; ++c) { ex[c] = __expf(logits[c] - m); sum += ex[c]; }
        float inv = 1.f / sum;
        #pragma unroll
        for (int c = 0; c < 5; ++c) out[(size_t)b * 5 + c] = ex[c] * inv;
    }
}

extern "C" void kernel_launch(void* const* d_in, const int* in_sizes, int n_in,
                              void* d_out, int out_size, void* d_ws, size_t ws_size,
                              hipStream_t stream) {
    const float* x     = (const float*)d_in[0];
    const float* bn_g  = (const float*)d_in[1];
    const float* bn_b  = (const float*)d_in[2];
    const float* bn_m  = (const float*)d_in[3];
    const float* bn_v  = (const float*)d_in[4];
    const float* frw1  = (const float*)d_in[5];
    const float* frb1  = (const float*)d_in[6];
    const float* frw2  = (const float*)d_in[7];
    const float* frb2  = (const float*)d_in[8];
    const float* frw3  = (const float*)d_in[9];
    const float* frb3  = (const float*)d_in[10];
    const float* fow1  = (const float*)d_in[11];
    const float* fob1  = (const float*)d_in[12];
    const float* fow2  = (const float*)d_in[13];
    const float* fob2  = (const float*)d_in[14];
    const float* fow3  = (const float*)d_in[15];
    const float* fob3  = (const float*)d_in[16];
    const float* fcw1  = (const float*)d_in[17];
    const float* fcb1  = (const float*)d_in[18];
    const float* fcw2  = (const float*)d_in[19];
    const float* fcb2  = (const float*)d_in[20];

    const int B = in_sizes[0] / (NCONST * NF);   // 512

    convint_fused<<<dim3(B), dim3(BLK), 0, stream>>>(
        x, bn_g, bn_b, bn_m, bn_v,
        frw1, frb1, frw2, frb2, frw3, frb3,
        fow1, fob1, fow2, fob2, fow3, fob3,
        fcw1, fcb1, fcw2, fcb2,
        (float*)d_out);
}

// Round 13
// 60.647 us; speedup vs baseline: 3.5131x; 1.0217x over previous
//
#include <hip/hip_runtime.h>
#include <math.h>

#define NCONST 100
#define NF     16
#define BLK    512

typedef _Float16 f16;
typedef _Float16 f16x8 __attribute__((ext_vector_type(8)));
typedef _Float16 f16x4 __attribute__((ext_vector_type(4)));
typedef float    f32x16 __attribute__((ext_vector_type(16)));

// One block per batch element, 512 threads (8 waves).
// R12 analysis: VALUBusy/MfmaUtil are CU-aggregated (x4 SIMDs) -> per-SIMD
// pipes ~85-90% idle; edge phase is dependency-latency-bound (one serial
// chain/wave). This round: ILP-2 -- each wave interleaves receivers
// (base, base+50) as two independent chains (lean R12 core: perm'd W2 so
// D1 regs ARE the MFMA2 A-frag; transposed MFMA2; biases folded at k=30/k2=15).
// VGPR est ~90 < 128 cap at (512,4). Spill tripwire: WRITE_SIZE >> 24KB.
__global__ __launch_bounds__(BLK, 4) void convint_fused(
    const float* __restrict__ x,
    const float* __restrict__ bn_g, const float* __restrict__ bn_b,
    const float* __restrict__ bn_m, const float* __restrict__ bn_v,
    const float* __restrict__ frw1, const float* __restrict__ frb1,
    const float* __restrict__ frw2, const float* __restrict__ frb2,
    const float* __restrict__ frw3, const float* __restrict__ frb3,
    const float* __restrict__ fow1, const float* __restrict__ fob1,
    const float* __restrict__ fow2, const float* __restrict__ fob2,
    const float* __restrict__ fow3, const float* __restrict__ fob3,
    const float* __restrict__ fcw1, const float* __restrict__ fcb1,
    const float* __restrict__ fcw2, const float* __restrict__ fcb2,
    float* __restrict__ out)
{
    __shared__ float xbn[NCONST][NF];
    __shared__ float upool[7200];
    __shared__ float aggF[NCONST * 8];
    __shared__ float fcin[8];
    __shared__ float hfc[48];
    __shared__ float logits[8];

    char* const PrB = (char*)upool;           // 8000 B, swizzled 16B slots
    char* const PsB = PrB + 8000;             // 8000 B
    float (*const foh1)[48] = (float (*)[48])upool;
    float (*const foh2)[24] = (float (*)[24])(upool + 4800);

    const int b   = blockIdx.x;
    const int tid = threadIdx.x;
    const float* xb = x + (size_t)b * (NCONST * NF);

    for (int idx = tid; idx < NCONST * NF; idx += BLK) {
        int f = idx & 15;
        float sc = rsqrtf(bn_v[f] + 1e-3f) * bn_g[f];
        xbn[idx >> 4][f] = (xb[idx] - bn_m[f]) * sc + bn_b[f];
    }
    if (tid < 8) fcin[tid] = 0.f;
    __syncthreads();

    // ---- proj (R9-verified): Pr/Ps f16 rows of 40 halves, swizzled ----
    for (int idx = tid; idx < 1600; idx += BLK) {
        int n   = idx >> 4;
        int rem = idx & 15;
        int sel = rem >> 3;
        int oq  = rem & 7;
        int o0  = oq * 4;
        float xs[16];
        {
            const float4* xv = (const float4*)(&xbn[n][0]);
            float4 x0 = xv[0], x1 = xv[1], x2 = xv[2], x3 = xv[3];
            xs[0]=x0.x; xs[1]=x0.y; xs[2]=x0.z; xs[3]=x0.w;
            xs[4]=x1.x; xs[5]=x1.y; xs[6]=x1.z; xs[7]=x1.w;
            xs[8]=x2.x; xs[9]=x2.y; xs[10]=x2.z; xs[11]=x2.w;
            xs[12]=x3.x; xs[13]=x3.y; xs[14]=x3.z; xs[15]=x3.w;
        }
        float acc0 = (!sel) ? frb1[o0 + 0] : 0.f;
        float acc1 = (!sel) ? frb1[o0 + 1] : 0.f;
        float acc2 = (!sel && oq < 7) ? frb1[o0 + 2] : 0.f;
        float acc3 = (!sel && oq < 7) ? frb1[o0 + 3] : 0.f;
        const float* wbase = frw1 + sel * 16 * 30;
        const int wcol2 = (oq < 7) ? o0 + 2 : 28;
        #pragma unroll
        for (int f = 0; f < 16; ++f) {
            const float* wr = wbase + f * 30;
            float2 wa = *(const float2*)(wr + o0);
            float2 wb = *(const float2*)(wr + wcol2);
            acc0 = fmaf(xs[f], wa.x, acc0);
            acc1 = fmaf(xs[f], wa.y, acc1);
            acc2 = fmaf(xs[f], wb.x, acc2);
            acc3 = fmaf(xs[f], wb.y, acc3);
        }
        f16x4 hv;
        hv[0] = (f16)acc0;
        hv[1] = (f16)acc1;
        hv[2] = (oq < 7) ? (f16)acc2 : (sel ? (f16)0.f : (f16)1.f);  // half30: bias carrier
        hv[3] = (oq < 7) ? (f16)acc3 : (f16)0.f;                     // half31: 0 (k-pad)
        int slot = oq >> 1;
        int sw = (slot & 2) | ((slot ^ (n >> 3)) & 1);
        *(f16x4*)((sel ? PsB : PrB) + n * 80 + sw * 16 + (oq & 1) * 8) = hv;
    }
    __syncthreads();

    // ---- edge phase: ILP-2 receivers per wave ----
    {
        const int l  = tid & 63;
        const int wv = tid >> 6;
        const int e  = l & 31;
        const int hi = l >> 5;

        // permuted W2 column for this A-row: swap [4..7] <-> [8..11]
        const int o2p = (e >= 4 && e < 12) ? (e ^ 12) : e;
        const bool o2v = (o2p < 15);
        const int  o2c = o2v ? o2p : 0;
        const bool o3v = (e < 6);
        const int  o3c = o3v ? e : 0;

        f16x8 bf1a, bf1b, bf2p;
        #pragma unroll
        for (int m = 0; m < 8; ++m) {
            int ka  = hi * 8 + m;          // 0..15
            int kb_ = 16 + ka;             // 16..31
            bf1a[m] = o2v ? (f16)frw2[ka * 15 + o2c] : (f16)0.f;
            f16 wb = (f16)0.f;
            if (o2v) {
                if (kb_ < 30)       wb = (f16)frw2[kb_ * 15 + o2c];
                else if (kb_ == 30) wb = (f16)frb2[o2c];         // b2 rides k=30
            }
            bf1b[m] = wb;
            f16 w3 = (f16)0.f;
            if (o3v) {
                if (ka < 15)       w3 = (f16)frw3[ka * 6 + o3c];
                else               w3 = (f16)frb3[o3c];          // b3 rides k2=15
            }
            bf2p[m] = w3;
        }
        f32x16 cz;
        #pragma unroll
        for (int r = 0; r < 16; ++r) cz[r] = 0.f;
        const float gtail = (e < 3) ? 1.f : 0.f;   // tb=3 valid senders 96..98

        for (int base = wv; base < 50; base += 8) {
            const int iA = base, iB = base + 50;
            const char* prpA = PrB + iA * 80 + ((hi ^ ((iA >> 3) & 1)) * 16);
            const char* prpB = PrB + iB * 80 + ((hi ^ ((iB >> 3) & 1)) * 16);
            f16x8 praA = *(const f16x8*)prpA;
            f16x8 prbA = *(const f16x8*)(prpA + 32);
            f16x8 praB = *(const f16x8*)prpB;
            f16x8 prbB = *(const f16x8*)(prpB + 32);
            float a0 = 0.f, a1 = 0.f, a2r = 0.f, a3 = 0.f;
            float b0 = 0.f, b1 = 0.f, b2r = 0.f, b3 = 0.f;

            int jA = iA + 1 + e; if (jA >= 100) jA -= 100;
            int jB = iB + 1 + e; if (jB >= 100) jB -= 100;
            #pragma unroll
            for (int tb = 0; tb < 4; ++tb) {
                const char* pspA = PsB + jA * 80 + ((hi ^ ((jA >> 3) & 1)) * 16);
                const char* pspB = PsB + jB * 80 + ((hi ^ ((jB >> 3) & 1)) * 16);
                f16x8 psaA = *(const f16x8*)pspA;
                f16x8 psbA = *(const f16x8*)(pspA + 32);
                f16x8 psaB = *(const f16x8*)pspB;
                f16x8 psbB = *(const f16x8*)(pspB + 32);

                f16x8 h1aA = praA + psaA, h1bA = prbA + psbA;
                f16x8 h1aB = praB + psaB, h1bB = prbB + psbB;
                #pragma unroll
                for (int m = 0; m < 8; ++m) {
                    h1aA[m] = (h1aA[m] > (f16)0.f) ? h1aA[m] : (f16)0.f;
                    h1bA[m] = (h1bA[m] > (f16)0.f) ? h1bA[m] : (f16)0.f;
                    h1aB[m] = (h1aB[m] > (f16)0.f) ? h1aB[m] : (f16)0.f;
                    h1bB[m] = (h1bB[m] > (f16)0.f) ? h1bB[m] : (f16)0.f;
                }
                // Two independent MFMA1 chains
                f32x16 c1A = __builtin_amdgcn_mfma_f32_32x32x16_f16(bf1a, h1aA, cz, 0, 0, 0);
                f32x16 c1B = __builtin_amdgcn_mfma_f32_32x32x16_f16(bf1a, h1aB, cz, 0, 0, 0);
                c1A = __builtin_amdgcn_mfma_f32_32x32x16_f16(bf1b, h1bA, c1A, 0, 0, 0);
                c1B = __builtin_amdgcn_mfma_f32_32x32x16_f16(bf1b, h1bB, c1B, 0, 0, 0);

                union { int w[4]; f16x8 v; } aA, aB;
                aA.w[0] = __builtin_bit_cast(int, __builtin_amdgcn_cvt_pkrtz(c1A[0], c1A[1]));
                aA.w[1] = __builtin_bit_cast(int, __builtin_amdgcn_cvt_pkrtz(c1A[2], c1A[3]));
                aA.w[2] = __builtin_bit_cast(int, __builtin_amdgcn_cvt_pkrtz(c1A[4], c1A[5]));
                aA.w[3] = __builtin_bit_cast(int, __builtin_amdgcn_cvt_pkrtz(c1A[6], c1A[7]));
                aB.w[0] = __builtin_bit_cast(int, __builtin_amdgcn_cvt_pkrtz(c1B[0], c1B[1]));
                aB.w[1] = __builtin_bit_cast(int, __builtin_amdgcn_cvt_pkrtz(c1B[2], c1B[3]));
                aB.w[2] = __builtin_bit_cast(int, __builtin_amdgcn_cvt_pkrtz(c1B[4], c1B[5]));
                aB.w[3] = __builtin_bit_cast(int, __builtin_amdgcn_cvt_pkrtz(c1B[6], c1B[7]));
                #pragma unroll
                for (int m = 0; m < 8; ++m) {
                    aA.v[m] = (aA.v[m] > (f16)0.f) ? aA.v[m] : (f16)0.f;
                    aB.v[m] = (aB.v[m] > (f16)0.f) ? aB.v[m] : (f16)0.f;
                }
                aA.v[7] = hi ? (f16)1.f : aA.v[7];   // k2=15 bias slot
                aB.v[7] = hi ? (f16)1.f : aB.v[7];

                f32x16 c2A = __builtin_amdgcn_mfma_f32_32x32x16_f16(bf2p, aA.v, cz, 0, 0, 0);
                f32x16 c2B = __builtin_amdgcn_mfma_f32_32x32x16_f16(bf2p, aB.v, cz, 0, 0, 0);

                if (tb < 3) {
                    a0 += fmaxf(c2A[0], 0.f);  a1 += fmaxf(c2A[1], 0.f);
                    a2r += fmaxf(c2A[2], 0.f); a3 += fmaxf(c2A[3], 0.f);
                    b0 += fmaxf(c2B[0], 0.f);  b1 += fmaxf(c2B[1], 0.f);
                    b2r += fmaxf(c2B[2], 0.f); b3 += fmaxf(c2B[3], 0.f);
                } else {
                    a0 = fmaf(gtail, fmaxf(c2A[0], 0.f), a0);
                    a1 = fmaf(gtail, fmaxf(c2A[1], 0.f), a1);
                    a2r = fmaf(gtail, fmaxf(c2A[2], 0.f), a2r);
                    a3 = fmaf(gtail, fmaxf(c2A[3], 0.f), a3);
                    b0 = fmaf(gtail, fmaxf(c2B[0], 0.f), b0);
                    b1 = fmaf(gtail, fmaxf(c2B[1], 0.f), b1);
                    b2r = fmaf(gtail, fmaxf(c2B[2], 0.f), b2r);
                    b3 = fmaf(gtail, fmaxf(c2B[3], 0.f), b3);
                }
                jA += 32; if (jA >= 100) jA -= 100;
                jB += 32; if (jB >= 100) jB -= 100;
            }
            // sum over 32 edge-lanes (stays within each 32-half)
            #pragma unroll
            for (int mk = 1; mk <= 16; mk <<= 1) {
                a0 += __shfl_xor(a0, mk);  a1 += __shfl_xor(a1, mk);
                a2r += __shfl_xor(a2r, mk); a3 += __shfl_xor(a3, mk);
                b0 += __shfl_xor(b0, mk);  b1 += __shfl_xor(b1, mk);
                b2r += __shfl_xor(b2r, mk); b3 += __shfl_xor(b3, mk);
            }
            if (l == 0) {
                float4 v; v.x = a0; v.y = a1; v.z = a2r; v.w = a3;
                *(float4*)&aggF[iA * 8] = v;
                float4 w; w.x = b0; w.y = b1; w.z = b2r; w.w = b3;
                *(float4*)&aggF[iB * 8] = w;
            } else if (l == 32) {
                float2 v; v.x = a0; v.y = a1;
                *(float2*)&aggF[iA * 8 + 4] = v;
                float2 w; w.x = b0; w.y = b1;
                *(float2*)&aggF[iB * 8 + 4] = w;
            }
        }
    }
    __syncthreads();

    // ---- fo + fc (R9-verified) ----
    for (int idx = tid; idx < NCONST * 45; idx += BLK) {
        int n = idx / 45, o = idx - n * 45;
        float acc = fob1[o];
        const float4* xv = (const float4*)(&xbn[n][0]);
        #pragma unroll
        for (int q = 0; q < 4; ++q) {
            float4 xq = xv[q];
            acc = fmaf(xq.x, fow1[(4 * q + 0) * 45 + o], acc);
            acc = fmaf(xq.y, fow1[(4 * q + 1) * 45 + o], acc);
            acc = fmaf(xq.z, fow1[(4 * q + 2) * 45 + o], acc);
            acc = fmaf(xq.w, fow1[(4 * q + 3) * 45 + o], acc);
        }
        const float4 g0 = *(const float4*)(&aggF[n * 8]);
        const float2 g1 = *(const float2*)(&aggF[n * 8 + 4]);
        acc = fmaf(g0.x, fow1[16 * 45 + o], acc);
        acc = fmaf(g0.y, fow1[17 * 45 + o], acc);
        acc = fmaf(g0.z, fow1[18 * 45 + o], acc);
        acc = fmaf(g0.w, fow1[19 * 45 + o], acc);
        acc = fmaf(g1.x, fow1[20 * 45 + o], acc);
        acc = fmaf(g1.y, fow1[21 * 45 + o], acc);
        foh1[n][o] = fmaxf(acc, 0.f);
    }
    __syncthreads();
    for (int idx = tid; idx < NCONST * 22; idx += BLK) {
        int n = idx / 22, o = idx - n * 22;
        float acc = fob2[o];
        const float4* hv = (const float4*)(&foh1[n][0]);
        #pragma unroll
        for (int q = 0; q < 11; ++q) {
            float4 h4 = hv[q];
            acc = fmaf(h4.x, fow2[(4 * q + 0) * 22 + o], acc);
            acc = fmaf(h4.y, fow2[(4 * q + 1) * 22 + o], acc);
            acc = fmaf(h4.z, fow2[(4 * q + 2) * 22 + o], acc);
            acc = fmaf(h4.w, fow2[(4 * q + 3) * 22 + o], acc);
        }
        acc = fmaf(foh1[n][44], fow2[44 * 22 + o], acc);
        foh2[n][o] = fmaxf(acc, 0.f);
    }
    __syncthreads();
    for (int idx = tid; idx < NCONST * 6; idx += BLK) {
        int n = idx / 6, c = idx - n * 6;
        float acc = fob3[c];
        const float4* hv = (const float4*)(&foh2[n][0]);
        #pragma unroll
        for (int q = 0; q < 5; ++q) {
            float4 h4 = hv[q];
            acc = fmaf(h4.x, fow3[(4 * q + 0) * 6 + c], acc);
            acc = fmaf(h4.y, fow3[(4 * q + 1) * 6 + c], acc);
            acc = fmaf(h4.z, fow3[(4 * q + 2) * 6 + c], acc);
            acc = fmaf(h4.w, fow3[(4 * q + 3) * 6 + c], acc);
        }
        acc = fmaf(foh2[n][20], fow3[20 * 6 + c], acc);
        acc = fmaf(foh2[n][21], fow3[21 * 6 + c], acc);
        atomicAdd(&fcin[c], fmaxf(acc, 0.f));
    }
    __syncthreads();
    if (tid < 48) {
        float acc = fcb1[tid];
        #pragma unroll
        for (int k = 0; k < 6; ++k) acc = fmaf(fcin[k], fcw1[k * 48 + tid], acc);
        hfc[tid] = fmaxf(acc, 0.f);
    }
    __syncthreads();
    if (tid < 5) {
        float acc = fcb2[tid];
        #pragma unroll
        for (int k = 0; k < 48; ++k) acc = fmaf(hfc[k], fcw2[k * 5 + tid], acc);
        logits[tid] = acc;
    }
    __syncthreads();
    if (tid == 0) {
        float m = logits[0];
        #pragma unroll
        for (int c = 1; c < 5; ++c) m = fmaxf(m, logits[c]);
        float ex[5], sum = 0.f;
        #pragma unroll
        for (int c = 0; c < 5; ++c) { ex[c] = __expf(logits[c] - m); sum += ex[c]; }
        float inv = 1.f / sum;
        #pragma unroll
        for (int c = 0; c < 5; ++c) out[(size_t)b * 5 + c] = ex[c] * inv;
    }
}

extern "C" void kernel_launch(void* const* d_in, const int* in_sizes, int n_in,
                              void* d_out, int out_size, void* d_ws, size_t ws_size,
                              hipStream_t stream) {
    const float* x     = (const float*)d_in[0];
    const float* bn_g  = (const float*)d_in[1];
    const float* bn_b  = (const float*)d_in[2];
    const float* bn_m  = (const float*)d_in[3];
    const float* bn_v  = (const float*)d_in[4];
    const float* frw1  = (const float*)d_in[5];
    const float* frb1  = (const float*)d_in[6];
    const float* frw2  = (const float*)d_in[7];
    const float* frb2  = (const float*)d_in[8];
    const float* frw3  = (const float*)d_in[9];
    const float* frb3  = (const float*)d_in[10];
    const float* fow1  = (const float*)d_in[11];
    const float* fob1  = (const float*)d_in[12];
    const float* fow2  = (const float*)d_in[13];
    const float* fob2  = (const float*)d_in[14];
    const float* fow3  = (const float*)d_in[15];
    const float* fob3  = (const float*)d_in[16];
    const float* fcw1  = (const float*)d_in[17];
    const float* fcb1  = (const float*)d_in[18];
    const float* fcw2  = (const float*)d_in[19];
    const float* fcb2  = (const float*)d_in[20];

    const int B = in_sizes[0] / (NCONST * NF);   // 512

    convint_fused<<<dim3(B), dim3(BLK), 0, stream>>>(
        x, bn_g, bn_b, bn_m, bn_v,
        frw1, frb1, frw2, frb2, frw3, frb3,
        fow1, fob1, fow2, fob2, fow3, fob3,
        fcw1, fcb1, fcw2, fcb2,
        (float*)d_out);
}